// Round 14
// baseline (109.253 us; speedup 1.0000x reference)
//
#include <hip/hip_runtime.h>

// Problem constants: N=50000, D=64, R=3, E=800000
#define N_NODES 50000
#define DFEAT   64
#define NREL    3
#define NEDGE   800000
#define OUT_COLS 256                 // (R+1)*D floats per output row
#define BROWS   128                  // rows per bucket
#define NBUCK   ((N_NODES + BROWS - 1) / BROWS)   // 391
#define TB      (NREL * NBUCK)       // 1173
#define SRTCAP  2560                 // accum LDS sorted-record capacity
#define SEGCAP  2560                 // fixed per-bucket segment capacity (mean 2046, +11 sigma)
#define SCAT_BLOCKS 196
#define SCHUNK  ((NEDGE + SCAT_BLOCKS - 1) / SCAT_BLOCKS)   // 4082
#define SCAP    4096                 // scatter LDS sort capacity >= SCHUNK

static __device__ inline unsigned short f2bf(float f) {
    unsigned u = __float_as_uint(f);
    unsigned r = u + 0x7FFFu + ((u >> 16) & 1u);   // round-to-nearest-even
    return (unsigned short)(r >> 16);
}

// ---------------- common kernels ----------------

__global__ void zero_counts_kernel(int* __restrict__ counts) {
    int i = blockIdx.x * 256 + threadIdx.x;
    if (i < TB) counts[i] = 0;
}

// x (f32) -> xb (bf16), streaming
__global__ void cvt_kernel(const float4* __restrict__ x4, ushort4* __restrict__ xb4) {
    int i = blockIdx.x * 256 + threadIdx.x;
    if (i >= N_NODES * DFEAT / 4) return;
    float4 v = x4[i];
    ushort4 o;
    o.x = f2bf(v.x); o.y = f2bf(v.y); o.z = f2bf(v.z); o.w = f2bf(v.w);
    xb4[i] = o;
}

// grid (128, NREL), block 256. LDS histogram per block (int4 edge reads).
// Only used on the non-segmented fallback path.
__global__ void count_kernel(const int* __restrict__ rows, int* __restrict__ counts) {
    __shared__ int hist[NBUCK];
    int rel = blockIdx.y;
    int tid = threadIdx.x;
    for (int i = tid; i < NBUCK; i += 256) hist[i] = 0;
    __syncthreads();
    const int4* rr4 = (const int4*)(rows + rel * NEDGE);
    for (int e = blockIdx.x * 256 + tid; e < NEDGE / 4; e += gridDim.x * 256) {
        int4 r = rr4[e];
        atomicAdd(&hist[r.x >> 7], 1);
        atomicAdd(&hist[r.y >> 7], 1);
        atomicAdd(&hist[r.z >> 7], 1);
        atomicAdd(&hist[r.w >> 7], 1);
    }
    __syncthreads();
    for (int i = tid; i < NBUCK; i += 256)
        if (hist[i]) atomicAdd(&counts[rel * NBUCK + i], hist[i]);
}

// single block of 256. counts[TB] -> offsets[TB+1]; cursor = copy of offsets.
// Only used on the non-segmented fallback path.
__global__ void scan_kernel(const int* __restrict__ counts,
                            int* __restrict__ offsets,
                            int* __restrict__ cursor) {
    __shared__ int part[256];
    const int PER = (TB + 255) / 256;   // 5
    int t = threadIdx.x;
    int base = t * PER;
    int loc[PER];
    int s = 0;
    for (int k = 0; k < PER; ++k) {
        int idx = base + k;
        int v = (idx < TB) ? counts[idx] : 0;
        loc[k] = s;
        s += v;
    }
    part[t] = s;
    __syncthreads();
    for (int off = 1; off < 256; off <<= 1) {
        int v = 0;
        if (t >= off) v = part[t - off];
        __syncthreads();
        if (t >= off) part[t] += v;
        __syncthreads();
    }
    int excl = (t == 0) ? 0 : part[t - 1];
    for (int k = 0; k < PER; ++k) {
        int idx = base + k;
        if (idx < TB) {
            int v = excl + loc[k];
            offsets[idx] = v;
            cursor[idx]  = v;
        }
    }
    if (t == 255) offsets[TB] = part[255];
}

// grid (SCAT_BLOCKS, NREL), block 512. Counting-sort the chunk's records by
// bucket in LDS, then write out LINEARLY (coalesced). SEG=true: destination
// is bucket-fixed segment recs[(rel*NBUCK+bk)*SEGCAP + off], cursor starts at
// 0 (becomes per-bucket count). SEG=false: cursor holds global offsets.
template <bool SEG>
__global__ void scatter_kernel(const int* __restrict__ rows,
                               const int* __restrict__ cols,
                               const float* __restrict__ vals,
                               int* __restrict__ cursor,
                               uint2* __restrict__ recs) {
    __shared__ int   hist[512];      // bucket hist -> scatter cursor
    __shared__ int   scanb[512];     // inclusive-scan buffer
    __shared__ int   basei[512];     // per-bucket reserved base
    __shared__ int   binstart[512];  // local start per bucket
    __shared__ uint2 srt[SCAP];      // 32 KB bucket-sorted records

    int rel = blockIdx.y;
    int tid = threadIdx.x;
    hist[tid] = 0;
    __syncthreads();

    const int*   rr = rows + rel * NEDGE;
    const int*   cc = cols + rel * NEDGE;
    const float* vv = vals + rel * NEDGE;
    int e0 = blockIdx.x * SCHUNK;
    int e1 = min(e0 + SCHUNK, NEDGE);
    int c  = e1 - e0;

    // pass A: bucket histogram
    for (int e = e0 + tid; e < e1; e += 512)
        atomicAdd(&hist[rr[e] >> 7], 1);
    __syncthreads();

    // per-bucket reservation + keep hist for scan
    int myh = hist[tid];
    basei[tid] = (tid < NBUCK && myh > 0) ? atomicAdd(&cursor[rel * NBUCK + tid], myh) : 0;
    scanb[tid] = myh;
    __syncthreads();
    // Hillis-Steele inclusive scan over 512
    for (int off = 1; off < 512; off <<= 1) {
        int v = (tid >= off) ? scanb[tid - off] : 0;
        __syncthreads();
        scanb[tid] += v;
        __syncthreads();
    }
    binstart[tid] = scanb[tid] - myh;   // exclusive
    hist[tid] = binstart[tid];          // becomes scatter cursor
    __syncthreads();

    // pass B: scatter into bucket-sorted LDS (bk stashed in bits 23..31)
    for (int e = e0 + tid; e < e1; e += 512) {
        int row = rr[e];
        int bk  = row >> 7;
        int pos = atomicAdd(&hist[bk], 1);
        srt[pos] = make_uint2(((unsigned)bk << 23) |
                              ((unsigned)cc[e] << 7) |
                              (unsigned)(row & 127),
                              __float_as_uint(vv[e]));
    }
    __syncthreads();

    // linear write-out: consecutive i in a bucket -> consecutive dst
    for (int i = tid; i < c; i += 512) {
        uint2 u = srt[i];
        int bk  = u.x >> 23;
        int off = basei[bk] + (i - binstart[bk]);
        if (SEG) {
            if (off < SEGCAP)   // +11 sigma guard, statistically never taken
                recs[(rel * NBUCK + bk) * SEGCAP + off] =
                    make_uint2(u.x & 0x7FFFFFu, u.y);
        } else {
            recs[off] = make_uint2(u.x & 0x7FFFFFu, u.y);
        }
    }
}

// ---- accum helpers: 8 records per wave-instruction, 8-lane groups ----
// Lane = oct*8 + fl. Record j+oct; lane covers features 8fl..8fl+7 via one
// 16B uint4 load of bf16 (or 2x float4 for f32). Accumulators s[0..7] are
// accessed with compile-time indices only (full unroll) -> stay in VGPRs.
template <bool BF16>
__device__ __forceinline__ void acc8full(const uint2* __restrict__ srt, int j,
                                         int oct, int fl,
                                         const ushort* __restrict__ xb,
                                         const float* __restrict__ xf,
                                         float (&s)[8]) {
    uint2 a = srt[j + oct];
    unsigned base8 = ((a.x >> 7) << 6) + (fl << 3);   // ushort/float units
    float v = __uint_as_float(a.y);
    if (BF16) {
        uint4 u = *(const uint4*)(xb + base8);        // 16B, 8 bf16
        s[0] = fmaf(v, __uint_as_float(u.x << 16),        s[0]);
        s[1] = fmaf(v, __uint_as_float(u.x & 0xFFFF0000u), s[1]);
        s[2] = fmaf(v, __uint_as_float(u.y << 16),        s[2]);
        s[3] = fmaf(v, __uint_as_float(u.y & 0xFFFF0000u), s[3]);
        s[4] = fmaf(v, __uint_as_float(u.z << 16),        s[4]);
        s[5] = fmaf(v, __uint_as_float(u.z & 0xFFFF0000u), s[5]);
        s[6] = fmaf(v, __uint_as_float(u.w << 16),        s[6]);
        s[7] = fmaf(v, __uint_as_float(u.w & 0xFFFF0000u), s[7]);
    } else {
        float4 f0 = *(const float4*)(xf + base8);
        float4 f1 = *(const float4*)(xf + base8 + 4);
        s[0] = fmaf(v, f0.x, s[0]); s[1] = fmaf(v, f0.y, s[1]);
        s[2] = fmaf(v, f0.z, s[2]); s[3] = fmaf(v, f0.w, s[3]);
        s[4] = fmaf(v, f1.x, s[4]); s[5] = fmaf(v, f1.y, s[5]);
        s[6] = fmaf(v, f1.z, s[6]); s[7] = fmaf(v, f1.w, s[7]);
    }
}

template <bool BF16>
__device__ __forceinline__ void acc8tail(const uint2* __restrict__ srt, int j, int rem,
                                         int oct, int fl,
                                         const ushort* __restrict__ xb,
                                         const float* __restrict__ xf,
                                         float (&s)[8]) {
    uint2 a = srt[(oct < rem) ? (j + oct) : j];
    unsigned base8 = ((a.x >> 7) << 6) + (fl << 3);
    float v = (oct < rem) ? __uint_as_float(a.y) : 0.f;
    if (BF16) {
        uint4 u = *(const uint4*)(xb + base8);
        s[0] = fmaf(v, __uint_as_float(u.x << 16),        s[0]);
        s[1] = fmaf(v, __uint_as_float(u.x & 0xFFFF0000u), s[1]);
        s[2] = fmaf(v, __uint_as_float(u.y << 16),        s[2]);
        s[3] = fmaf(v, __uint_as_float(u.y & 0xFFFF0000u), s[3]);
        s[4] = fmaf(v, __uint_as_float(u.z << 16),        s[4]);
        s[5] = fmaf(v, __uint_as_float(u.z & 0xFFFF0000u), s[5]);
        s[6] = fmaf(v, __uint_as_float(u.w << 16),        s[6]);
        s[7] = fmaf(v, __uint_as_float(u.w & 0xFFFF0000u), s[7]);
    } else {
        float4 f0 = *(const float4*)(xf + base8);
        float4 f1 = *(const float4*)(xf + base8 + 4);
        s[0] = fmaf(v, f0.x, s[0]); s[1] = fmaf(v, f0.y, s[1]);
        s[2] = fmaf(v, f0.z, s[2]); s[3] = fmaf(v, f0.w, s[3]);
        s[4] = fmaf(v, f1.x, s[4]); s[5] = fmaf(v, f1.y, s[5]);
        s[6] = fmaf(v, f1.z, s[6]); s[7] = fmaf(v, f1.w, s[7]);
    }
}

// grid TB blocks, block 512 (8 waves). Counting-sort the bucket's records by
// LOCAL ROW into LDS, then wave w register-accumulates rows [16w,16w+16) in
// PAIRS (interleaved A/B). 8-lane group oct processes record j+oct; one 16B
// load covers 8 features -> 8 records serviced per wave instruction (half the
// L2 requests of the 4-way scheme). Row end: 3 shfl_xor levels (8,16,32);
// oct-0 lanes store two coalesced float4 per row. rel==0 blocks also copy x
// into out[:,192:256] (fused copyx).
template <bool BF16, bool SEG>
__global__ void accum3_kernel(const void* __restrict__ xsrc,
                              const float* __restrict__ xf32,
                              const int* __restrict__ meta,
                              const uint2* __restrict__ recs,
                              float* __restrict__ out) {
    __shared__ uint2 srt[SRTCAP];        // 20 KB
    __shared__ int bins[BROWS];
    __shared__ int rowoff[BROWS + 1];

    int b    = blockIdx.x;
    int rel  = b / NBUCK;
    int buck = b % NBUCK;
    int tid  = threadIdx.x;
    int lane = tid & 63, w = tid >> 6;
    int oct  = lane >> 3;        // record j+oct
    int fl   = lane & 7;         // features 8fl .. 8fl+7
    int row0 = buck * BROWS;

    int start, end;
    if (SEG) {
        start = b * SEGCAP;
        end   = start + min(meta[b], SEGCAP);
    } else {
        start = meta[b];
        end   = meta[b + 1];
    }
    int total = end - start;

    const ushort* xb = (const ushort*)xsrc;
    const float*  xf = (const float*)xsrc;

    if (total <= SRTCAP) {
        if (tid < BROWS) bins[tid] = 0;
        __syncthreads();
        // pass 1: per-row histogram (stream recs from global)
        for (int i = start + tid; i < end; i += 512)
            atomicAdd(&bins[recs[i].x & 127], 1);
        __syncthreads();
        // exclusive scan of 128 bins
        if (tid == 0) {
            int s = 0;
            rowoff[0] = 0;
            for (int k = 0; k < BROWS; ++k) {
                int v = bins[k];
                bins[k] = s;          // becomes scatter cursor
                s += v;
                rowoff[k + 1] = s;
            }
        }
        __syncthreads();
        // pass 2: scatter into row-sorted LDS copy (segment is L2-hot)
        for (int i = start + tid; i < end; i += 512) {
            uint2 r = recs[i];
            int pos = atomicAdd(&bins[r.x & 127], 1);
            srt[pos] = r;
        }
        __syncthreads();

        // replay: wave w owns 16 consecutive local rows, processed in PAIRS
        int rl0 = w * 16;
        for (int rl = rl0; rl < rl0 + 16; rl += 2) {
            int rowA = row0 + rl;
            if (rowA >= N_NODES) break;
            int rowB = rowA + 1;
            bool hasB = (rowB < N_NODES);
            int jA = rowoff[rl],     eA = rowoff[rl + 1];
            int jB = rowoff[rl + 1], eB = rowoff[rl + 2];
            if (!hasB) { jB = 0; eB = 0; }
            float sa[8] = {0.f, 0.f, 0.f, 0.f, 0.f, 0.f, 0.f, 0.f};
            float sb[8] = {0.f, 0.f, 0.f, 0.f, 0.f, 0.f, 0.f, 0.f};
            int nA = (eA - jA) >> 3;
            int nB = (eB - jB) >> 3;
            int n  = min(nA, nB);
            for (int k = 0; k < n; ++k) {
                acc8full<BF16>(srt, jA + (k << 3), oct, fl, xb, xf, sa);
                acc8full<BF16>(srt, jB + (k << 3), oct, fl, xb, xf, sb);
            }
            jA += n << 3; jB += n << 3;
            for (int k = 0; k < nA - n; ++k)
                acc8full<BF16>(srt, jA + (k << 3), oct, fl, xb, xf, sa);
            jA += (nA - n) << 3;
            for (int k = 0; k < nB - n; ++k)
                acc8full<BF16>(srt, jB + (k << 3), oct, fl, xb, xf, sb);
            jB += (nB - n) << 3;
            int remA = eA - jA;
            if (remA > 0)
                acc8tail<BF16>(srt, jA, remA, oct, fl, xb, xf, sa);
            int remB = eB - jB;
            if (remB > 0)
                acc8tail<BF16>(srt, jB, remB, oct, fl, xb, xf, sb);
            // combine 8 oct-group accumulators per row (3 butterfly levels)
            #pragma unroll
            for (int q = 0; q < 8; ++q) {
                sa[q] += __shfl_xor(sa[q], 8);
                sa[q] += __shfl_xor(sa[q], 16);
                sa[q] += __shfl_xor(sa[q], 32);
                sb[q] += __shfl_xor(sb[q], 8);
                sb[q] += __shfl_xor(sb[q], 16);
                sb[q] += __shfl_xor(sb[q], 32);
            }
            if (oct == 0) {
                float* oA = out + (long)rowA * OUT_COLS + rel * DFEAT + (fl << 3);
                float4 a0; a0.x = sa[0]; a0.y = sa[1]; a0.z = sa[2]; a0.w = sa[3];
                float4 a1; a1.x = sa[4]; a1.y = sa[5]; a1.z = sa[6]; a1.w = sa[7];
                *(float4*)oA = a0;
                *(float4*)(oA + 4) = a1;
                if (hasB) {
                    float* oB = out + (long)rowB * OUT_COLS + rel * DFEAT + (fl << 3);
                    float4 b0; b0.x = sb[0]; b0.y = sb[1]; b0.z = sb[2]; b0.w = sb[3];
                    float4 b1; b1.x = sb[4]; b1.y = sb[5]; b1.z = sb[6]; b1.w = sb[7];
                    *(float4*)oB = b0;
                    *(float4*)(oB + 4) = b1;
                }
            }
        }
    } else {
        // overflow slow path (only reachable on !SEG; statistically never):
        // per-row scan straight from global, one feature per lane.
        int rl0 = w * 16;
        for (int rl = rl0; rl < rl0 + 16; ++rl) {
            int row = row0 + rl;
            if (row >= N_NODES) break;
            float s0 = 0.f;
            for (int j = start; j < end; ++j) {
                uint2 a = recs[j];
                if ((int)(a.x & 127) == rl) {
                    unsigned ia = ((a.x >> 7) << 6) + lane;
                    float xa = BF16 ? __uint_as_float(((unsigned)xb[ia]) << 16) : xf[ia];
                    s0 = fmaf(__uint_as_float(a.y), xa, s0);
                }
            }
            out[(long)row * OUT_COLS + rel * DFEAT + lane] = s0;
        }
    }

    // fused copyx: rel 0 blocks copy x rows (f32 source) into out[:,192:256]
    if (rel == 0) {
        int rl0 = w * 16;
        for (int rl = rl0; rl < rl0 + 16; ++rl) {
            int row = row0 + rl;
            if (row >= N_NODES) break;
            out[(long)row * OUT_COLS + 192 + lane] = xf32[row * DFEAT + lane];
        }
    }
}

// ---------------- fallback path (no workspace) ----------------

__global__ void init_out_kernel(const float4* __restrict__ x4, float4* __restrict__ out4) {
    int j = blockIdx.x * blockDim.x + threadIdx.x;
    if (j >= N_NODES * 64) return;
    int row = j >> 6, c = j & 63;
    float4 v;
    if (c < 48) v = make_float4(0.f, 0.f, 0.f, 0.f);
    else        v = x4[row * 16 + (c - 48)];
    out4[j] = v;
}

__global__ void scatter_spmm_kernel(const float* __restrict__ x,
                                    const int* __restrict__ rows,
                                    const int* __restrict__ cols,
                                    const float* __restrict__ vals,
                                    float* __restrict__ out) {
    int idx = blockIdx.x * blockDim.x + threadIdx.x;
    int e = idx >> 4, sub = idx & 15;
    if (e >= NEDGE) return;
    int r = blockIdx.y;
    long base = (long)r * NEDGE + e;
    int row = rows[base], col = cols[base];
    float val = vals[base];
    const float4 xv = *reinterpret_cast<const float4*>(x + (long)col * DFEAT + sub * 4);
    float* o = out + (long)row * OUT_COLS + r * DFEAT + sub * 4;
    atomicAdd(o + 0, val * xv.x);
    atomicAdd(o + 1, val * xv.y);
    atomicAdd(o + 2, val * xv.z);
    atomicAdd(o + 3, val * xv.w);
}

// ---------------- launch ----------------

extern "C" void kernel_launch(void* const* d_in, const int* in_sizes, int n_in,
                              void* d_out, int out_size, void* d_ws, size_t ws_size,
                              hipStream_t stream) {
    const float* x         = (const float*)d_in[0];
    const int*   edge_rows = (const int*)d_in[1];
    const int*   edge_cols = (const int*)d_in[2];
    const float* edge_vals = (const float*)d_in[3];
    float* out = (float*)d_out;

    const size_t XB_BYTES     = (size_t)N_NODES * DFEAT * sizeof(ushort);  // 6.4 MB
    // segmented layout: cursor @0 (TB ints), xb @32768, segs @32768+XB
    const size_t SEG_REC_OFF  = 32768 + XB_BYTES;                          // 6,432,768
    const size_t SEG_REC_BYTES= (size_t)TB * SEGCAP * sizeof(uint2);       // 24.0 MB
    const size_t NEED_SEG     = SEG_REC_OFF + SEG_REC_BYTES;               // ~30.5 MB
    // offsets layout: ctrl @0, recs @32768, xb after
    const size_t REC_OFF      = 32768;
    const size_t REC_BYTES    = (size_t)NREL * NEDGE * sizeof(uint2);      // 19.2 MB
    const size_t XB_OFF       = REC_OFF + REC_BYTES;
    const size_t NEED_FULL    = XB_OFF + XB_BYTES;                         // ~25.6 MB
    const size_t NEED_MIN     = REC_OFF + REC_BYTES;                       // ~19.2 MB

    if (ws_size >= NEED_SEG) {
        // ---- segmented path: no count, no scan ----
        int*    cursor = (int*)d_ws;                         // TB ints, zeroed
        ushort* xb     = (ushort*)((char*)d_ws + 32768);
        uint2*  recs   = (uint2*)((char*)d_ws + SEG_REC_OFF);

        zero_counts_kernel<<<(TB + 255) / 256, 256, 0, stream>>>(cursor);
        cvt_kernel<<<(N_NODES * DFEAT / 4 + 255) / 256, 256, 0, stream>>>(
            (const float4*)x, (ushort4*)xb);
        scatter_kernel<true><<<dim3(SCAT_BLOCKS, NREL), 512, 0, stream>>>(
            edge_rows, edge_cols, edge_vals, cursor, recs);
        accum3_kernel<true, true><<<TB, 512, 0, stream>>>(
            xb, x, cursor, recs, out);
    } else if (ws_size >= NEED_MIN) {
        // ---- offsets path ----
        int*   counts  = (int*)d_ws;            // TB ints
        int*   offsets = counts + TB;           // TB+1 ints
        int*   cursor  = offsets + TB + 1;      // TB ints  (< 32 KB total)
        uint2* recs    = (uint2*)((char*)d_ws + REC_OFF);
        ushort* xb     = (ushort*)((char*)d_ws + XB_OFF);
        bool   bf16ok  = (ws_size >= NEED_FULL);

        zero_counts_kernel<<<(TB + 255) / 256, 256, 0, stream>>>(counts);
        if (bf16ok)
            cvt_kernel<<<(N_NODES * DFEAT / 4 + 255) / 256, 256, 0, stream>>>(
                (const float4*)x, (ushort4*)xb);
        count_kernel<<<dim3(128, NREL), 256, 0, stream>>>(edge_rows, counts);
        scan_kernel<<<1, 256, 0, stream>>>(counts, offsets, cursor);
        scatter_kernel<false><<<dim3(SCAT_BLOCKS, NREL), 512, 0, stream>>>(
            edge_rows, edge_cols, edge_vals, cursor, recs);
        if (bf16ok)
            accum3_kernel<true, false><<<TB, 512, 0, stream>>>(xb, x, offsets, recs, out);
        else
            accum3_kernel<false, false><<<TB, 512, 0, stream>>>(x, x, offsets, recs, out);
    } else {
        // Fallback: global-atomic scatter (correct, slower)
        {
            int total = N_NODES * 64;
            init_out_kernel<<<(total + 255) / 256, 256, 0, stream>>>(
                (const float4*)x, (float4*)out);
        }
        {
            int threads_per_rel = NEDGE * 16;
            int blocks = (threads_per_rel + 255) / 256;
            dim3 grid(blocks, NREL);
            scatter_spmm_kernel<<<grid, 256, 0, stream>>>(
                x, edge_rows, edge_cols, edge_vals, out);
        }
    }
}

// Round 15
// 95.979 us; speedup vs baseline: 1.1383x; 1.1383x over previous
//
#include <hip/hip_runtime.h>

// Problem constants: N=50000, D=64, R=3, E=800000
#define N_NODES 50000
#define DFEAT   64
#define NREL    3
#define NEDGE   800000
#define OUT_COLS 256                 // (R+1)*D floats per output row
#define BROWS   128                  // rows per bucket
#define NBUCK   ((N_NODES + BROWS - 1) / BROWS)   // 391
#define TB      (NREL * NBUCK)       // 1173
#define SRTCAP  2560                 // accum LDS sorted-record capacity
#define SEGCAP  2560                 // fixed per-bucket segment capacity (mean 2046, +11 sigma)
#define SCAT_BLOCKS 196
#define SCHUNK  ((NEDGE + SCAT_BLOCKS - 1) / SCAT_BLOCKS)   // 4082
#define SCAP    4096                 // scatter LDS sort capacity >= SCHUNK

static __device__ inline unsigned short f2bf(float f) {
    unsigned u = __float_as_uint(f);
    unsigned r = u + 0x7FFFu + ((u >> 16) & 1u);   // round-to-nearest-even
    return (unsigned short)(r >> 16);
}
static __device__ inline float bf2f(unsigned short h) {
    return __uint_as_float(((unsigned)h) << 16);
}

// ---------------- common kernels ----------------

__global__ void zero_counts_kernel(int* __restrict__ counts) {
    int i = blockIdx.x * 256 + threadIdx.x;
    if (i < TB) counts[i] = 0;
}

// x (f32) -> xb (bf16), streaming
__global__ void cvt_kernel(const float4* __restrict__ x4, ushort4* __restrict__ xb4) {
    int i = blockIdx.x * 256 + threadIdx.x;
    if (i >= N_NODES * DFEAT / 4) return;
    float4 v = x4[i];
    ushort4 o;
    o.x = f2bf(v.x); o.y = f2bf(v.y); o.z = f2bf(v.z); o.w = f2bf(v.w);
    xb4[i] = o;
}

// grid (128, NREL), block 256. LDS histogram per block (int4 edge reads).
// Only used on the non-segmented fallback path.
__global__ void count_kernel(const int* __restrict__ rows, int* __restrict__ counts) {
    __shared__ int hist[NBUCK];
    int rel = blockIdx.y;
    int tid = threadIdx.x;
    for (int i = tid; i < NBUCK; i += 256) hist[i] = 0;
    __syncthreads();
    const int4* rr4 = (const int4*)(rows + rel * NEDGE);
    for (int e = blockIdx.x * 256 + tid; e < NEDGE / 4; e += gridDim.x * 256) {
        int4 r = rr4[e];
        atomicAdd(&hist[r.x >> 7], 1);
        atomicAdd(&hist[r.y >> 7], 1);
        atomicAdd(&hist[r.z >> 7], 1);
        atomicAdd(&hist[r.w >> 7], 1);
    }
    __syncthreads();
    for (int i = tid; i < NBUCK; i += 256)
        if (hist[i]) atomicAdd(&counts[rel * NBUCK + i], hist[i]);
}

// single block of 256. counts[TB] -> offsets[TB+1]; cursor = copy of offsets.
// Only used on the non-segmented fallback path.
__global__ void scan_kernel(const int* __restrict__ counts,
                            int* __restrict__ offsets,
                            int* __restrict__ cursor) {
    __shared__ int part[256];
    const int PER = (TB + 255) / 256;   // 5
    int t = threadIdx.x;
    int base = t * PER;
    int loc[PER];
    int s = 0;
    for (int k = 0; k < PER; ++k) {
        int idx = base + k;
        int v = (idx < TB) ? counts[idx] : 0;
        loc[k] = s;
        s += v;
    }
    part[t] = s;
    __syncthreads();
    for (int off = 1; off < 256; off <<= 1) {
        int v = 0;
        if (t >= off) v = part[t - off];
        __syncthreads();
        if (t >= off) part[t] += v;
        __syncthreads();
    }
    int excl = (t == 0) ? 0 : part[t - 1];
    for (int k = 0; k < PER; ++k) {
        int idx = base + k;
        if (idx < TB) {
            int v = excl + loc[k];
            offsets[idx] = v;
            cursor[idx]  = v;
        }
    }
    if (t == 255) offsets[TB] = part[255];
}

// grid (SCAT_BLOCKS, NREL), block 512. Counting-sort the chunk's records by
// bucket in LDS, then write out LINEARLY (coalesced). SEG=true: destination
// is bucket-fixed segment recs[(rel*NBUCK+bk)*SEGCAP + off], cursor starts at
// 0 (becomes per-bucket count). SEG=false: cursor holds global offsets
// (offsets layout). Bucket id stashed in rec.x bits 23..31 inside LDS.
template <bool SEG>
__global__ void scatter_kernel(const int* __restrict__ rows,
                               const int* __restrict__ cols,
                               const float* __restrict__ vals,
                               int* __restrict__ cursor,
                               uint2* __restrict__ recs) {
    __shared__ int   hist[512];      // bucket hist -> scatter cursor
    __shared__ int   scanb[512];     // inclusive-scan buffer
    __shared__ int   basei[512];     // per-bucket reserved base
    __shared__ int   binstart[512];  // local start per bucket
    __shared__ uint2 srt[SCAP];      // 32 KB bucket-sorted records

    int rel = blockIdx.y;
    int tid = threadIdx.x;
    hist[tid] = 0;
    __syncthreads();

    const int*   rr = rows + rel * NEDGE;
    const int*   cc = cols + rel * NEDGE;
    const float* vv = vals + rel * NEDGE;
    int e0 = blockIdx.x * SCHUNK;
    int e1 = min(e0 + SCHUNK, NEDGE);
    int c  = e1 - e0;

    // pass A: bucket histogram
    for (int e = e0 + tid; e < e1; e += 512)
        atomicAdd(&hist[rr[e] >> 7], 1);
    __syncthreads();

    // per-bucket reservation + keep hist for scan
    int myh = hist[tid];
    basei[tid] = (tid < NBUCK && myh > 0) ? atomicAdd(&cursor[rel * NBUCK + tid], myh) : 0;
    scanb[tid] = myh;
    __syncthreads();
    // Hillis-Steele inclusive scan over 512
    for (int off = 1; off < 512; off <<= 1) {
        int v = (tid >= off) ? scanb[tid - off] : 0;
        __syncthreads();
        scanb[tid] += v;
        __syncthreads();
    }
    binstart[tid] = scanb[tid] - myh;   // exclusive
    hist[tid] = binstart[tid];          // becomes scatter cursor
    __syncthreads();

    // pass B: scatter into bucket-sorted LDS (bk stashed in bits 23..31)
    for (int e = e0 + tid; e < e1; e += 512) {
        int row = rr[e];
        int bk  = row >> 7;
        int pos = atomicAdd(&hist[bk], 1);
        srt[pos] = make_uint2(((unsigned)bk << 23) |
                              ((unsigned)cc[e] << 7) |
                              (unsigned)(row & 127),
                              __float_as_uint(vv[e]));
    }
    __syncthreads();

    // linear write-out: consecutive i in a bucket -> consecutive dst
    for (int i = tid; i < c; i += 512) {
        uint2 u = srt[i];
        int bk  = u.x >> 23;
        int off = basei[bk] + (i - binstart[bk]);
        if (SEG) {
            if (off < SEGCAP)   // +11 sigma guard, statistically never taken
                recs[(rel * NBUCK + bk) * SEGCAP + off] =
                    make_uint2(u.x & 0x7FFFFFu, u.y);
        } else {
            recs[off] = make_uint2(u.x & 0x7FFFFFu, u.y);
        }
    }
}

// ---- accum helpers: 4 records per wave-instruction, 16-lane groups ----
template <bool BF16>
__device__ __forceinline__ void acc4full(const uint2* __restrict__ srt, int j,
                                         int quarter, int fl,
                                         const ushort* __restrict__ xb,
                                         const float* __restrict__ xf,
                                         float& s0, float& s1, float& s2, float& s3) {
    uint2 a = srt[j + quarter];
    unsigned base4 = ((a.x >> 7) << 6) + (fl << 2);
    float v = __uint_as_float(a.y);
    if (BF16) {
        ushort4 u = *(const ushort4*)(xb + base4);
        s0 = fmaf(v, bf2f(u.x), s0);
        s1 = fmaf(v, bf2f(u.y), s1);
        s2 = fmaf(v, bf2f(u.z), s2);
        s3 = fmaf(v, bf2f(u.w), s3);
    } else {
        float4 f = *(const float4*)(xf + base4);
        s0 = fmaf(v, f.x, s0);
        s1 = fmaf(v, f.y, s1);
        s2 = fmaf(v, f.z, s2);
        s3 = fmaf(v, f.w, s3);
    }
}

template <bool BF16>
__device__ __forceinline__ void acc4tail(const uint2* __restrict__ srt, int j, int rem,
                                         int quarter, int fl,
                                         const ushort* __restrict__ xb,
                                         const float* __restrict__ xf,
                                         float& s0, float& s1, float& s2, float& s3) {
    uint2 a = srt[(quarter < rem) ? (j + quarter) : j];
    unsigned base4 = ((a.x >> 7) << 6) + (fl << 2);
    float v = (quarter < rem) ? __uint_as_float(a.y) : 0.f;
    if (BF16) {
        ushort4 u = *(const ushort4*)(xb + base4);
        s0 = fmaf(v, bf2f(u.x), s0);
        s1 = fmaf(v, bf2f(u.y), s1);
        s2 = fmaf(v, bf2f(u.z), s2);
        s3 = fmaf(v, bf2f(u.w), s3);
    } else {
        float4 f = *(const float4*)(xf + base4);
        s0 = fmaf(v, f.x, s0);
        s1 = fmaf(v, f.y, s1);
        s2 = fmaf(v, f.z, s2);
        s3 = fmaf(v, f.w, s3);
    }
}

// grid TB blocks, block 512 (8 waves). Counting-sort the bucket's records by
// LOCAL ROW into LDS, then wave w register-accumulates rows [16w,16w+16) in
// PAIRS: rows rl,rl+1 interleaved (8 accumulators, unroll 2 -> 8 independent
// row-gathers in flight). 16-lane group q processes record j+q; each lane
// covers 4 features via one 8B ushort4 bf16 load. Row end: shfl_xor(16,32)
// combine; quarter-0 lanes store one coalesced float4 per row. rel==0 blocks
// also copy x into out[:,192:256] (fused copyx).
// SEG=true: meta = per-bucket counts, segment base = b*SEGCAP.
// SEG=false: meta = offsets[TB+1].
template <bool BF16, bool SEG>
__global__ void accum3_kernel(const void* __restrict__ xsrc,
                              const float* __restrict__ xf32,
                              const int* __restrict__ meta,
                              const uint2* __restrict__ recs,
                              float* __restrict__ out) {
    __shared__ uint2 srt[SRTCAP];        // 20 KB
    __shared__ int bins[BROWS];
    __shared__ int rowoff[BROWS + 1];

    int b    = blockIdx.x;
    int rel  = b / NBUCK;
    int buck = b % NBUCK;
    int tid  = threadIdx.x;
    int lane = tid & 63, w = tid >> 6;
    int quarter = lane >> 4;     // record j+quarter
    int fl   = lane & 15;        // features 4fl .. 4fl+3
    int row0 = buck * BROWS;

    int start, end;
    if (SEG) {
        start = b * SEGCAP;
        end   = start + min(meta[b], SEGCAP);
    } else {
        start = meta[b];
        end   = meta[b + 1];
    }
    int total = end - start;

    const ushort* xb = (const ushort*)xsrc;
    const float*  xf = (const float*)xsrc;

    if (total <= SRTCAP) {
        if (tid < BROWS) bins[tid] = 0;
        __syncthreads();
        // pass 1: per-row histogram (stream recs from global)
        for (int i = start + tid; i < end; i += 512)
            atomicAdd(&bins[recs[i].x & 127], 1);
        __syncthreads();
        // exclusive scan of 128 bins
        if (tid == 0) {
            int s = 0;
            rowoff[0] = 0;
            for (int k = 0; k < BROWS; ++k) {
                int v = bins[k];
                bins[k] = s;          // becomes scatter cursor
                s += v;
                rowoff[k + 1] = s;
            }
        }
        __syncthreads();
        // pass 2: scatter into row-sorted LDS copy (segment is L2-hot)
        for (int i = start + tid; i < end; i += 512) {
            uint2 r = recs[i];
            int pos = atomicAdd(&bins[r.x & 127], 1);
            srt[pos] = r;
        }
        __syncthreads();

        // replay: wave w owns 16 consecutive local rows, processed in PAIRS
        int rl0 = w * 16;
        for (int rl = rl0; rl < rl0 + 16; rl += 2) {
            int rowA = row0 + rl;
            if (rowA >= N_NODES) break;
            int rowB = rowA + 1;
            bool hasB = (rowB < N_NODES);
            int jA = rowoff[rl],     eA = rowoff[rl + 1];
            int jB = rowoff[rl + 1], eB = rowoff[rl + 2];
            if (!hasB) { jB = 0; eB = 0; }
            float a0 = 0.f, a1 = 0.f, a2 = 0.f, a3 = 0.f;
            float b0 = 0.f, b1 = 0.f, b2 = 0.f, b3 = 0.f;
            int nA = (eA - jA) >> 2;
            int nB = (eB - jB) >> 2;
            int n  = min(nA, nB);
            #pragma unroll 2
            for (int k = 0; k < n; ++k) {
                acc4full<BF16>(srt, jA + (k << 2), quarter, fl, xb, xf, a0, a1, a2, a3);
                acc4full<BF16>(srt, jB + (k << 2), quarter, fl, xb, xf, b0, b1, b2, b3);
            }
            jA += n << 2; jB += n << 2;
            #pragma unroll 2
            for (int k = 0; k < nA - n; ++k)
                acc4full<BF16>(srt, jA + (k << 2), quarter, fl, xb, xf, a0, a1, a2, a3);
            jA += (nA - n) << 2;
            #pragma unroll 2
            for (int k = 0; k < nB - n; ++k)
                acc4full<BF16>(srt, jB + (k << 2), quarter, fl, xb, xf, b0, b1, b2, b3);
            jB += (nB - n) << 2;
            int remA = eA - jA;
            if (remA > 0)
                acc4tail<BF16>(srt, jA, remA, quarter, fl, xb, xf, a0, a1, a2, a3);
            int remB = eB - jB;
            if (remB > 0)
                acc4tail<BF16>(srt, jB, remB, quarter, fl, xb, xf, b0, b1, b2, b3);
            // combine 4 quarter-wave accumulators per row
            a0 += __shfl_xor(a0, 16); a0 += __shfl_xor(a0, 32);
            a1 += __shfl_xor(a1, 16); a1 += __shfl_xor(a1, 32);
            a2 += __shfl_xor(a2, 16); a2 += __shfl_xor(a2, 32);
            a3 += __shfl_xor(a3, 16); a3 += __shfl_xor(a3, 32);
            b0 += __shfl_xor(b0, 16); b0 += __shfl_xor(b0, 32);
            b1 += __shfl_xor(b1, 16); b1 += __shfl_xor(b1, 32);
            b2 += __shfl_xor(b2, 16); b2 += __shfl_xor(b2, 32);
            b3 += __shfl_xor(b3, 16); b3 += __shfl_xor(b3, 32);
            if (quarter == 0) {
                float4 oA; oA.x = a0; oA.y = a1; oA.z = a2; oA.w = a3;
                *(float4*)(out + (long)rowA * OUT_COLS + rel * DFEAT + (fl << 2)) = oA;
                if (hasB) {
                    float4 oB; oB.x = b0; oB.y = b1; oB.z = b2; oB.w = b3;
                    *(float4*)(out + (long)rowB * OUT_COLS + rel * DFEAT + (fl << 2)) = oB;
                }
            }
        }
    } else {
        // overflow slow path (only reachable on !SEG; statistically never):
        // per-row scan straight from global, one feature per lane.
        int rl0 = w * 16;
        for (int rl = rl0; rl < rl0 + 16; ++rl) {
            int row = row0 + rl;
            if (row >= N_NODES) break;
            float s0 = 0.f;
            for (int j = start; j < end; ++j) {
                uint2 a = recs[j];
                if ((int)(a.x & 127) == rl) {
                    unsigned ia = ((a.x >> 7) << 6) + lane;
                    float xa = BF16 ? bf2f(xb[ia]) : xf[ia];
                    s0 = fmaf(__uint_as_float(a.y), xa, s0);
                }
            }
            out[(long)row * OUT_COLS + rel * DFEAT + lane] = s0;
        }
    }

    // fused copyx: rel 0 blocks copy x rows (f32 source) into out[:,192:256]
    if (rel == 0) {
        int rl0 = w * 16;
        for (int rl = rl0; rl < rl0 + 16; ++rl) {
            int row = row0 + rl;
            if (row >= N_NODES) break;
            out[(long)row * OUT_COLS + 192 + lane] = xf32[row * DFEAT + lane];
        }
    }
}

// ---------------- fallback path (no workspace) ----------------

__global__ void init_out_kernel(const float4* __restrict__ x4, float4* __restrict__ out4) {
    int j = blockIdx.x * blockDim.x + threadIdx.x;
    if (j >= N_NODES * 64) return;
    int row = j >> 6, c = j & 63;
    float4 v;
    if (c < 48) v = make_float4(0.f, 0.f, 0.f, 0.f);
    else        v = x4[row * 16 + (c - 48)];
    out4[j] = v;
}

__global__ void scatter_spmm_kernel(const float* __restrict__ x,
                                    const int* __restrict__ rows,
                                    const int* __restrict__ cols,
                                    const float* __restrict__ vals,
                                    float* __restrict__ out) {
    int idx = blockIdx.x * blockDim.x + threadIdx.x;
    int e = idx >> 4, sub = idx & 15;
    if (e >= NEDGE) return;
    int r = blockIdx.y;
    long base = (long)r * NEDGE + e;
    int row = rows[base], col = cols[base];
    float val = vals[base];
    const float4 xv = *reinterpret_cast<const float4*>(x + (long)col * DFEAT + sub * 4);
    float* o = out + (long)row * OUT_COLS + r * DFEAT + sub * 4;
    atomicAdd(o + 0, val * xv.x);
    atomicAdd(o + 1, val * xv.y);
    atomicAdd(o + 2, val * xv.z);
    atomicAdd(o + 3, val * xv.w);
}

// ---------------- launch ----------------

extern "C" void kernel_launch(void* const* d_in, const int* in_sizes, int n_in,
                              void* d_out, int out_size, void* d_ws, size_t ws_size,
                              hipStream_t stream) {
    const float* x         = (const float*)d_in[0];
    const int*   edge_rows = (const int*)d_in[1];
    const int*   edge_cols = (const int*)d_in[2];
    const float* edge_vals = (const float*)d_in[3];
    float* out = (float*)d_out;

    const size_t XB_BYTES     = (size_t)N_NODES * DFEAT * sizeof(ushort);  // 6.4 MB
    // segmented layout: cursor @0 (TB ints), xb @32768, segs @32768+XB
    const size_t SEG_REC_OFF  = 32768 + XB_BYTES;                          // 6,432,768
    const size_t SEG_REC_BYTES= (size_t)TB * SEGCAP * sizeof(uint2);       // 24.0 MB
    const size_t NEED_SEG     = SEG_REC_OFF + SEG_REC_BYTES;               // ~30.5 MB
    // offsets layout: ctrl @0, recs @32768, xb after
    const size_t REC_OFF      = 32768;
    const size_t REC_BYTES    = (size_t)NREL * NEDGE * sizeof(uint2);      // 19.2 MB
    const size_t XB_OFF       = REC_OFF + REC_BYTES;
    const size_t NEED_FULL    = XB_OFF + XB_BYTES;                         // ~25.6 MB
    const size_t NEED_MIN     = REC_OFF + REC_BYTES;                       // ~19.2 MB

    if (ws_size >= NEED_SEG) {
        // ---- segmented path: no count, no scan ----
        int*    cursor = (int*)d_ws;                         // TB ints, zeroed
        ushort* xb     = (ushort*)((char*)d_ws + 32768);
        uint2*  recs   = (uint2*)((char*)d_ws + SEG_REC_OFF);

        zero_counts_kernel<<<(TB + 255) / 256, 256, 0, stream>>>(cursor);
        cvt_kernel<<<(N_NODES * DFEAT / 4 + 255) / 256, 256, 0, stream>>>(
            (const float4*)x, (ushort4*)xb);
        scatter_kernel<true><<<dim3(SCAT_BLOCKS, NREL), 512, 0, stream>>>(
            edge_rows, edge_cols, edge_vals, cursor, recs);
        accum3_kernel<true, true><<<TB, 512, 0, stream>>>(
            xb, x, cursor, recs, out);
    } else if (ws_size >= NEED_MIN) {
        // ---- offsets path ----
        int*   counts  = (int*)d_ws;            // TB ints
        int*   offsets = counts + TB;           // TB+1 ints
        int*   cursor  = offsets + TB + 1;      // TB ints  (< 32 KB total)
        uint2* recs    = (uint2*)((char*)d_ws + REC_OFF);
        ushort* xb     = (ushort*)((char*)d_ws + XB_OFF);
        bool   bf16ok  = (ws_size >= NEED_FULL);

        zero_counts_kernel<<<(TB + 255) / 256, 256, 0, stream>>>(counts);
        if (bf16ok)
            cvt_kernel<<<(N_NODES * DFEAT / 4 + 255) / 256, 256, 0, stream>>>(
                (const float4*)x, (ushort4*)xb);
        count_kernel<<<dim3(128, NREL), 256, 0, stream>>>(edge_rows, counts);
        scan_kernel<<<1, 256, 0, stream>>>(counts, offsets, cursor);
        scatter_kernel<false><<<dim3(SCAT_BLOCKS, NREL), 512, 0, stream>>>(
            edge_rows, edge_cols, edge_vals, cursor, recs);
        if (bf16ok)
            accum3_kernel<true, false><<<TB, 512, 0, stream>>>(xb, x, offsets, recs, out);
        else
            accum3_kernel<false, false><<<TB, 512, 0, stream>>>(x, x, offsets, recs, out);
    } else {
        // Fallback: global-atomic scatter (correct, slower)
        {
            int total = N_NODES * 64;
            init_out_kernel<<<(total + 255) / 256, 256, 0, stream>>>(
                (const float4*)x, (float4*)out);
        }
        {
            int threads_per_rel = NEDGE * 16;
            int blocks = (threads_per_rel + 255) / 256;
            dim3 grid(blocks, NREL);
            scatter_spmm_kernel<<<grid, 256, 0, stream>>>(
                x, edge_rows, edge_cols, edge_vals, out);
        }
    }
}

// Round 16
// 92.880 us; speedup vs baseline: 1.1763x; 1.0334x over previous
//
#include <hip/hip_runtime.h>

// Problem constants: N=50000, D=64, R=3, E=800000
#define N_NODES 50000
#define DFEAT   64
#define NREL    3
#define NEDGE   800000
#define OUT_COLS 256                 // (R+1)*D floats per output row
#define BROWS   128                  // rows per bucket
#define NBUCK   ((N_NODES + BROWS - 1) / BROWS)   // 391
#define TB      (NREL * NBUCK)       // 1173
#define SRTCAP  2560                 // accum LDS sorted-record capacity (= 512*5)
#define SEGCAP  2560                 // fixed per-bucket segment capacity (mean 2046, +11 sigma)
#define SCAT_BLOCKS 196
#define SCHUNK  ((NEDGE + SCAT_BLOCKS - 1) / SCAT_BLOCKS)   // 4082
#define SCAP    4096                 // scatter LDS sort capacity >= SCHUNK
#define INVALID 0x7FFFFFFFu

static __device__ inline unsigned short f2bf(float f) {
    unsigned u = __float_as_uint(f);
    unsigned r = u + 0x7FFFu + ((u >> 16) & 1u);   // round-to-nearest-even
    return (unsigned short)(r >> 16);
}
static __device__ inline float bf2f(unsigned short h) {
    return __uint_as_float(((unsigned)h) << 16);
}

// ---------------- common kernels ----------------

__global__ void zero_counts_kernel(int* __restrict__ counts) {
    int i = blockIdx.x * 256 + threadIdx.x;
    if (i < TB) counts[i] = 0;
}

// x (f32) -> xb (bf16), streaming
__global__ void cvt_kernel(const float4* __restrict__ x4, ushort4* __restrict__ xb4) {
    int i = blockIdx.x * 256 + threadIdx.x;
    if (i >= N_NODES * DFEAT / 4) return;
    float4 v = x4[i];
    ushort4 o;
    o.x = f2bf(v.x); o.y = f2bf(v.y); o.z = f2bf(v.z); o.w = f2bf(v.w);
    xb4[i] = o;
}

// grid (128, NREL), block 256. LDS histogram per block (int4 edge reads).
// Only used on the non-segmented fallback path.
__global__ void count_kernel(const int* __restrict__ rows, int* __restrict__ counts) {
    __shared__ int hist[NBUCK];
    int rel = blockIdx.y;
    int tid = threadIdx.x;
    for (int i = tid; i < NBUCK; i += 256) hist[i] = 0;
    __syncthreads();
    const int4* rr4 = (const int4*)(rows + rel * NEDGE);
    for (int e = blockIdx.x * 256 + tid; e < NEDGE / 4; e += gridDim.x * 256) {
        int4 r = rr4[e];
        atomicAdd(&hist[r.x >> 7], 1);
        atomicAdd(&hist[r.y >> 7], 1);
        atomicAdd(&hist[r.z >> 7], 1);
        atomicAdd(&hist[r.w >> 7], 1);
    }
    __syncthreads();
    for (int i = tid; i < NBUCK; i += 256)
        if (hist[i]) atomicAdd(&counts[rel * NBUCK + i], hist[i]);
}

// single block of 256. counts[TB] -> offsets[TB+1]; cursor = copy of offsets.
// Only used on the non-segmented fallback path.
__global__ void scan_kernel(const int* __restrict__ counts,
                            int* __restrict__ offsets,
                            int* __restrict__ cursor) {
    __shared__ int part[256];
    const int PER = (TB + 255) / 256;   // 5
    int t = threadIdx.x;
    int base = t * PER;
    int loc[PER];
    int s = 0;
    for (int k = 0; k < PER; ++k) {
        int idx = base + k;
        int v = (idx < TB) ? counts[idx] : 0;
        loc[k] = s;
        s += v;
    }
    part[t] = s;
    __syncthreads();
    for (int off = 1; off < 256; off <<= 1) {
        int v = 0;
        if (t >= off) v = part[t - off];
        __syncthreads();
        if (t >= off) part[t] += v;
        __syncthreads();
    }
    int excl = (t == 0) ? 0 : part[t - 1];
    for (int k = 0; k < PER; ++k) {
        int idx = base + k;
        if (idx < TB) {
            int v = excl + loc[k];
            offsets[idx] = v;
            cursor[idx]  = v;
        }
    }
    if (t == 255) offsets[TB] = part[255];
}

// grid (SCAT_BLOCKS, NREL), block 512. Counting-sort the chunk's records by
// bucket in LDS, then write out LINEARLY (coalesced). SEG=true: destination
// is bucket-fixed segment recs[(rel*NBUCK+bk)*SEGCAP + off], cursor starts at
// 0 (becomes per-bucket count). SEG=false: cursor holds global offsets.
template <bool SEG>
__global__ void scatter_kernel(const int* __restrict__ rows,
                               const int* __restrict__ cols,
                               const float* __restrict__ vals,
                               int* __restrict__ cursor,
                               uint2* __restrict__ recs) {
    __shared__ int   hist[512];      // bucket hist -> scatter cursor
    __shared__ int   scanb[512];     // inclusive-scan buffer
    __shared__ int   basei[512];     // per-bucket reserved base
    __shared__ int   binstart[512];  // local start per bucket
    __shared__ uint2 srt[SCAP];      // 32 KB bucket-sorted records

    int rel = blockIdx.y;
    int tid = threadIdx.x;
    hist[tid] = 0;
    __syncthreads();

    const int*   rr = rows + rel * NEDGE;
    const int*   cc = cols + rel * NEDGE;
    const float* vv = vals + rel * NEDGE;
    int e0 = blockIdx.x * SCHUNK;
    int e1 = min(e0 + SCHUNK, NEDGE);
    int c  = e1 - e0;

    // pass A: bucket histogram
    for (int e = e0 + tid; e < e1; e += 512)
        atomicAdd(&hist[rr[e] >> 7], 1);
    __syncthreads();

    // per-bucket reservation + keep hist for scan
    int myh = hist[tid];
    basei[tid] = (tid < NBUCK && myh > 0) ? atomicAdd(&cursor[rel * NBUCK + tid], myh) : 0;
    scanb[tid] = myh;
    __syncthreads();
    // Hillis-Steele inclusive scan over 512
    for (int off = 1; off < 512; off <<= 1) {
        int v = (tid >= off) ? scanb[tid - off] : 0;
        __syncthreads();
        scanb[tid] += v;
        __syncthreads();
    }
    binstart[tid] = scanb[tid] - myh;   // exclusive
    hist[tid] = binstart[tid];          // becomes scatter cursor
    __syncthreads();

    // pass B: scatter into bucket-sorted LDS (bk stashed in bits 23..31)
    for (int e = e0 + tid; e < e1; e += 512) {
        int row = rr[e];
        int bk  = row >> 7;
        int pos = atomicAdd(&hist[bk], 1);
        srt[pos] = make_uint2(((unsigned)bk << 23) |
                              ((unsigned)cc[e] << 7) |
                              (unsigned)(row & 127),
                              __float_as_uint(vv[e]));
    }
    __syncthreads();

    // linear write-out: consecutive i in a bucket -> consecutive dst
    for (int i = tid; i < c; i += 512) {
        uint2 u = srt[i];
        int bk  = u.x >> 23;
        int off = basei[bk] + (i - binstart[bk]);
        if (SEG) {
            if (off < SEGCAP)   // +11 sigma guard, statistically never taken
                recs[(rel * NBUCK + bk) * SEGCAP + off] =
                    make_uint2(u.x & 0x7FFFFFu, u.y);
        } else {
            recs[off] = make_uint2(u.x & 0x7FFFFFu, u.y);
        }
    }
}

// ---- accum helpers: 4 records per wave-instruction, 16-lane groups ----
template <bool BF16>
__device__ __forceinline__ void acc4full(const uint2* __restrict__ srt, int j,
                                         int quarter, int fl,
                                         const ushort* __restrict__ xb,
                                         const float* __restrict__ xf,
                                         float& s0, float& s1, float& s2, float& s3) {
    uint2 a = srt[j + quarter];
    unsigned base4 = ((a.x >> 7) << 6) + (fl << 2);
    float v = __uint_as_float(a.y);
    if (BF16) {
        ushort4 u = *(const ushort4*)(xb + base4);
        s0 = fmaf(v, bf2f(u.x), s0);
        s1 = fmaf(v, bf2f(u.y), s1);
        s2 = fmaf(v, bf2f(u.z), s2);
        s3 = fmaf(v, bf2f(u.w), s3);
    } else {
        float4 f = *(const float4*)(xf + base4);
        s0 = fmaf(v, f.x, s0);
        s1 = fmaf(v, f.y, s1);
        s2 = fmaf(v, f.z, s2);
        s3 = fmaf(v, f.w, s3);
    }
}

template <bool BF16>
__device__ __forceinline__ void acc4tail(const uint2* __restrict__ srt, int j, int rem,
                                         int quarter, int fl,
                                         const ushort* __restrict__ xb,
                                         const float* __restrict__ xf,
                                         float& s0, float& s1, float& s2, float& s3) {
    uint2 a = srt[(quarter < rem) ? (j + quarter) : j];
    unsigned base4 = ((a.x >> 7) << 6) + (fl << 2);
    float v = (quarter < rem) ? __uint_as_float(a.y) : 0.f;
    if (BF16) {
        ushort4 u = *(const ushort4*)(xb + base4);
        s0 = fmaf(v, bf2f(u.x), s0);
        s1 = fmaf(v, bf2f(u.y), s1);
        s2 = fmaf(v, bf2f(u.z), s2);
        s3 = fmaf(v, bf2f(u.w), s3);
    } else {
        float4 f = *(const float4*)(xf + base4);
        s0 = fmaf(v, f.x, s0);
        s1 = fmaf(v, f.y, s1);
        s2 = fmaf(v, f.z, s2);
        s3 = fmaf(v, f.w, s3);
    }
}

// grid TB blocks, block 512 (8 waves). SEG path: SINGLE-PASS register-staged
// sort — each thread loads exactly 5 records (fixed trip count, static
// indices -> stays in VGPRs, no PromoteAlloca), builds the per-row LDS
// histogram from registers, scans, scatters from registers into row-sorted
// LDS. recs read ONCE from global (was twice); one fewer barrier. Replay
// unchanged: wave w register-accumulates rows [16w,16w+16) in PAIRS (rows
// rl,rl+1 interleaved, 8 accumulators); 16-lane group q processes record j+q,
// each lane covers 4 features via one 8B ushort4 bf16 load; shfl_xor(16,32)
// combine; quarter-0 lanes store one coalesced float4 per row. rel==0 blocks
// also copy x into out[:,192:256] (fused copyx).
template <bool BF16, bool SEG>
__global__ void accum3_kernel(const void* __restrict__ xsrc,
                              const float* __restrict__ xf32,
                              const int* __restrict__ meta,
                              const uint2* __restrict__ recs,
                              float* __restrict__ out) {
    __shared__ uint2 srt[SRTCAP];        // 20 KB
    __shared__ int bins[BROWS];
    __shared__ int rowoff[BROWS + 1];

    int b    = blockIdx.x;
    int rel  = b / NBUCK;
    int buck = b % NBUCK;
    int tid  = threadIdx.x;
    int lane = tid & 63, w = tid >> 6;
    int quarter = lane >> 4;     // record j+quarter
    int fl   = lane & 15;        // features 4fl .. 4fl+3
    int row0 = buck * BROWS;

    int start, end;
    if (SEG) {
        start = b * SEGCAP;
        end   = start + min(meta[b], SEGCAP);
    } else {
        start = meta[b];
        end   = meta[b + 1];
    }
    int total = end - start;

    const ushort* xb = (const ushort*)xsrc;
    const float*  xf = (const float*)xsrc;

    if (total <= SRTCAP) {
        if (tid < BROWS) bins[tid] = 0;

        if (SEG) {
            // ---- single-pass register-staged sort (SEG: total <= 2560) ----
            uint2 myrec[5];
            #pragma unroll
            for (int k = 0; k < 5; ++k) {
                int i = start + tid + k * 512;
                myrec[k] = (i < end) ? recs[i] : make_uint2(INVALID, 0);
            }
            __syncthreads();
            #pragma unroll
            for (int k = 0; k < 5; ++k)
                if (myrec[k].x != INVALID)
                    atomicAdd(&bins[myrec[k].x & 127], 1);
            __syncthreads();
            if (tid == 0) {
                int s = 0;
                rowoff[0] = 0;
                for (int k = 0; k < BROWS; ++k) {
                    int v = bins[k];
                    bins[k] = s;          // becomes scatter cursor
                    s += v;
                    rowoff[k + 1] = s;
                }
            }
            __syncthreads();
            #pragma unroll
            for (int k = 0; k < 5; ++k)
                if (myrec[k].x != INVALID) {
                    int pos = atomicAdd(&bins[myrec[k].x & 127], 1);
                    srt[pos] = myrec[k];
                }
            __syncthreads();
        } else {
            // ---- two-pass global sort (fallback path) ----
            __syncthreads();
            for (int i = start + tid; i < end; i += 512)
                atomicAdd(&bins[recs[i].x & 127], 1);
            __syncthreads();
            if (tid == 0) {
                int s = 0;
                rowoff[0] = 0;
                for (int k = 0; k < BROWS; ++k) {
                    int v = bins[k];
                    bins[k] = s;
                    s += v;
                    rowoff[k + 1] = s;
                }
            }
            __syncthreads();
            for (int i = start + tid; i < end; i += 512) {
                uint2 r = recs[i];
                int pos = atomicAdd(&bins[r.x & 127], 1);
                srt[pos] = r;
            }
            __syncthreads();
        }

        // replay: wave w owns 16 consecutive local rows, processed in PAIRS
        int rl0 = w * 16;
        for (int rl = rl0; rl < rl0 + 16; rl += 2) {
            int rowA = row0 + rl;
            if (rowA >= N_NODES) break;
            int rowB = rowA + 1;
            bool hasB = (rowB < N_NODES);
            int jA = rowoff[rl],     eA = rowoff[rl + 1];
            int jB = rowoff[rl + 1], eB = rowoff[rl + 2];
            if (!hasB) { jB = 0; eB = 0; }
            float a0 = 0.f, a1 = 0.f, a2 = 0.f, a3 = 0.f;
            float b0 = 0.f, b1 = 0.f, b2 = 0.f, b3 = 0.f;
            int nA = (eA - jA) >> 2;
            int nB = (eB - jB) >> 2;
            int n  = min(nA, nB);
            #pragma unroll 2
            for (int k = 0; k < n; ++k) {
                acc4full<BF16>(srt, jA + (k << 2), quarter, fl, xb, xf, a0, a1, a2, a3);
                acc4full<BF16>(srt, jB + (k << 2), quarter, fl, xb, xf, b0, b1, b2, b3);
            }
            jA += n << 2; jB += n << 2;
            #pragma unroll 2
            for (int k = 0; k < nA - n; ++k)
                acc4full<BF16>(srt, jA + (k << 2), quarter, fl, xb, xf, a0, a1, a2, a3);
            jA += (nA - n) << 2;
            #pragma unroll 2
            for (int k = 0; k < nB - n; ++k)
                acc4full<BF16>(srt, jB + (k << 2), quarter, fl, xb, xf, b0, b1, b2, b3);
            jB += (nB - n) << 2;
            int remA = eA - jA;
            if (remA > 0)
                acc4tail<BF16>(srt, jA, remA, quarter, fl, xb, xf, a0, a1, a2, a3);
            int remB = eB - jB;
            if (remB > 0)
                acc4tail<BF16>(srt, jB, remB, quarter, fl, xb, xf, b0, b1, b2, b3);
            // combine 4 quarter-wave accumulators per row
            a0 += __shfl_xor(a0, 16); a0 += __shfl_xor(a0, 32);
            a1 += __shfl_xor(a1, 16); a1 += __shfl_xor(a1, 32);
            a2 += __shfl_xor(a2, 16); a2 += __shfl_xor(a2, 32);
            a3 += __shfl_xor(a3, 16); a3 += __shfl_xor(a3, 32);
            b0 += __shfl_xor(b0, 16); b0 += __shfl_xor(b0, 32);
            b1 += __shfl_xor(b1, 16); b1 += __shfl_xor(b1, 32);
            b2 += __shfl_xor(b2, 16); b2 += __shfl_xor(b2, 32);
            b3 += __shfl_xor(b3, 16); b3 += __shfl_xor(b3, 32);
            if (quarter == 0) {
                float4 oA; oA.x = a0; oA.y = a1; oA.z = a2; oA.w = a3;
                *(float4*)(out + (long)rowA * OUT_COLS + rel * DFEAT + (fl << 2)) = oA;
                if (hasB) {
                    float4 oB; oB.x = b0; oB.y = b1; oB.z = b2; oB.w = b3;
                    *(float4*)(out + (long)rowB * OUT_COLS + rel * DFEAT + (fl << 2)) = oB;
                }
            }
        }
    } else {
        // overflow slow path (only reachable on !SEG; statistically never):
        // per-row scan straight from global, one feature per lane.
        int rl0 = w * 16;
        for (int rl = rl0; rl < rl0 + 16; ++rl) {
            int row = row0 + rl;
            if (row >= N_NODES) break;
            float s0 = 0.f;
            for (int j = start; j < end; ++j) {
                uint2 a = recs[j];
                if ((int)(a.x & 127) == rl) {
                    unsigned ia = ((a.x >> 7) << 6) + lane;
                    float xa = BF16 ? bf2f(xb[ia]) : xf[ia];
                    s0 = fmaf(__uint_as_float(a.y), xa, s0);
                }
            }
            out[(long)row * OUT_COLS + rel * DFEAT + lane] = s0;
        }
    }

    // fused copyx: rel 0 blocks copy x rows (f32 source) into out[:,192:256]
    if (rel == 0) {
        int rl0 = w * 16;
        for (int rl = rl0; rl < rl0 + 16; ++rl) {
            int row = row0 + rl;
            if (row >= N_NODES) break;
            out[(long)row * OUT_COLS + 192 + lane] = xf32[row * DFEAT + lane];
        }
    }
}

// ---------------- fallback path (no workspace) ----------------

__global__ void init_out_kernel(const float4* __restrict__ x4, float4* __restrict__ out4) {
    int j = blockIdx.x * blockDim.x + threadIdx.x;
    if (j >= N_NODES * 64) return;
    int row = j >> 6, c = j & 63;
    float4 v;
    if (c < 48) v = make_float4(0.f, 0.f, 0.f, 0.f);
    else        v = x4[row * 16 + (c - 48)];
    out4[j] = v;
}

__global__ void scatter_spmm_kernel(const float* __restrict__ x,
                                    const int* __restrict__ rows,
                                    const int* __restrict__ cols,
                                    const float* __restrict__ vals,
                                    float* __restrict__ out) {
    int idx = blockIdx.x * blockDim.x + threadIdx.x;
    int e = idx >> 4, sub = idx & 15;
    if (e >= NEDGE) return;
    int r = blockIdx.y;
    long base = (long)r * NEDGE + e;
    int row = rows[base], col = cols[base];
    float val = vals[base];
    const float4 xv = *reinterpret_cast<const float4*>(x + (long)col * DFEAT + sub * 4);
    float* o = out + (long)row * OUT_COLS + r * DFEAT + sub * 4;
    atomicAdd(o + 0, val * xv.x);
    atomicAdd(o + 1, val * xv.y);
    atomicAdd(o + 2, val * xv.z);
    atomicAdd(o + 3, val * xv.w);
}

// ---------------- launch ----------------

extern "C" void kernel_launch(void* const* d_in, const int* in_sizes, int n_in,
                              void* d_out, int out_size, void* d_ws, size_t ws_size,
                              hipStream_t stream) {
    const float* x         = (const float*)d_in[0];
    const int*   edge_rows = (const int*)d_in[1];
    const int*   edge_cols = (const int*)d_in[2];
    const float* edge_vals = (const float*)d_in[3];
    float* out = (float*)d_out;

    const size_t XB_BYTES     = (size_t)N_NODES * DFEAT * sizeof(ushort);  // 6.4 MB
    // segmented layout: cursor @0 (TB ints), xb @32768, segs @32768+XB
    const size_t SEG_REC_OFF  = 32768 + XB_BYTES;                          // 6,432,768
    const size_t SEG_REC_BYTES= (size_t)TB * SEGCAP * sizeof(uint2);       // 24.0 MB
    const size_t NEED_SEG     = SEG_REC_OFF + SEG_REC_BYTES;               // ~30.5 MB
    // offsets layout: ctrl @0, recs @32768, xb after
    const size_t REC_OFF      = 32768;
    const size_t REC_BYTES    = (size_t)NREL * NEDGE * sizeof(uint2);      // 19.2 MB
    const size_t XB_OFF       = REC_OFF + REC_BYTES;
    const size_t NEED_FULL    = XB_OFF + XB_BYTES;                         // ~25.6 MB
    const size_t NEED_MIN     = REC_OFF + REC_BYTES;                       // ~19.2 MB

    if (ws_size >= NEED_SEG) {
        // ---- segmented path: no count, no scan ----
        int*    cursor = (int*)d_ws;                         // TB ints, zeroed
        ushort* xb     = (ushort*)((char*)d_ws + 32768);
        uint2*  recs   = (uint2*)((char*)d_ws + SEG_REC_OFF);

        zero_counts_kernel<<<(TB + 255) / 256, 256, 0, stream>>>(cursor);
        cvt_kernel<<<(N_NODES * DFEAT / 4 + 255) / 256, 256, 0, stream>>>(
            (const float4*)x, (ushort4*)xb);
        scatter_kernel<true><<<dim3(SCAT_BLOCKS, NREL), 512, 0, stream>>>(
            edge_rows, edge_cols, edge_vals, cursor, recs);
        accum3_kernel<true, true><<<TB, 512, 0, stream>>>(
            xb, x, cursor, recs, out);
    } else if (ws_size >= NEED_MIN) {
        // ---- offsets path ----
        int*   counts  = (int*)d_ws;            // TB ints
        int*   offsets = counts + TB;           // TB+1 ints
        int*   cursor  = offsets + TB + 1;      // TB ints  (< 32 KB total)
        uint2* recs    = (uint2*)((char*)d_ws + REC_OFF);
        ushort* xb     = (ushort*)((char*)d_ws + XB_OFF);
        bool   bf16ok  = (ws_size >= NEED_FULL);

        zero_counts_kernel<<<(TB + 255) / 256, 256, 0, stream>>>(counts);
        if (bf16ok)
            cvt_kernel<<<(N_NODES * DFEAT / 4 + 255) / 256, 256, 0, stream>>>(
                (const float4*)x, (ushort4*)xb);
        count_kernel<<<dim3(128, NREL), 256, 0, stream>>>(edge_rows, counts);
        scan_kernel<<<1, 256, 0, stream>>>(counts, offsets, cursor);
        scatter_kernel<false><<<dim3(SCAT_BLOCKS, NREL), 512, 0, stream>>>(
            edge_rows, edge_cols, edge_vals, cursor, recs);
        if (bf16ok)
            accum3_kernel<true, false><<<TB, 512, 0, stream>>>(xb, x, offsets, recs, out);
        else
            accum3_kernel<false, false><<<TB, 512, 0, stream>>>(x, x, offsets, recs, out);
    } else {
        // Fallback: global-atomic scatter (correct, slower)
        {
            int total = N_NODES * 64;
            init_out_kernel<<<(total + 255) / 256, 256, 0, stream>>>(
                (const float4*)x, (float4*)out);
        }
        {
            int threads_per_rel = NEDGE * 16;
            int blocks = (threads_per_rel + 255) / 256;
            dim3 grid(blocks, NREL);
            scatter_spmm_kernel<<<grid, 256, 0, stream>>>(
                x, edge_rows, edge_cols, edge_vals, out);
        }
    }
}